// Round 3
// baseline (221.395 us; speedup 1.0000x reference)
//
#include <hip/hip_runtime.h>
#include <stdint.h>

// SupConLossWithPrototype on MI355X.
// Only NOVEL columns of S=F F^T/T are ever used:
//   novel i: sumS = sum_{j novel, j!=i} S_ij, sumE = sum_{j novel, j!=i} exp(S_ij)
//   base  i: sumE over novel j only
// This version: no compaction. Fz = novel ? bf16(5*log2e * f) : 0. Then
//   MFMA D = A(Fb raw bf16) x Fz^T  ->  exp2(D) sums directly; base columns
//   contribute exp2(0)=1 each, subtracted as (M - Nn) in k_final.
//   sum_j S_ij recovered exactly via linearity: dot(f_i, g), g = colsum(Fz).
// Pipeline: memset -> k_proto2 (P terms + Fb + Fz) -> k_colsum (g partials)
//           -> k_main (MFMA exp row sums) -> k_final (dots + loss).

#define M_TOT 8192
#define K_DIM 128
#define B_PRO 100
#define INV_T 5.0f                          // 1/TEMP
#define C_SCALE 7.2134752044448170f         // 5 * log2(e)
#define INV_C   0.1386294361119891f         // 1 / C_SCALE = ln2/5
#define CJ    512                           // column chunk per k_main block
#define LDA   136                           // k_main LDS row stride (bf16)
#define PS    136                           // k_proto2 proto LDS stride
#define FS    136                           // k_proto2 feat LDS stride

#if __has_builtin(__builtin_amdgcn_exp2f)
#define EXP2(x) __builtin_amdgcn_exp2f(x)
#else
#define EXP2(x) __expf((x) * 0.6931471805599453f)
#endif

typedef __attribute__((ext_vector_type(8))) short  short8;   // 8 bf16 (MFMA A/B frag)
typedef __attribute__((ext_vector_type(4))) float  floatx4;  // MFMA C/D frag

__device__ __forceinline__ float bf2f(unsigned short u) {
    union { unsigned int i; float f; } v; v.i = ((unsigned int)u) << 16; return v.f;
}
__device__ __forceinline__ unsigned short f2bf(float x) {   // RNE
    union { float f; unsigned int i; } v; v.f = x;
    return (unsigned short)((v.i + 0x7fffu + ((v.i >> 16) & 1u)) >> 16);
}
__device__ __forceinline__ float lo_bf(unsigned int u) {
    union { unsigned int i; float f; } v; v.i = u << 16; return v.f;
}
__device__ __forceinline__ float hi_bf(unsigned int u) {
    union { unsigned int i; float f; } v; v.i = u & 0xffff0000u; return v.f;
}

// ---------------------------------------------------------------- k_proto2
// 512 blocks x 256 thr; 16 feature rows per block. Emits: Psum/expPsum/PLab/
// nf per row, count (novel total), Fb = bf16(f), Fz = novel? bf16(C*f) : 0.
__global__ __launch_bounds__(256) void k_proto2(
        const float* __restrict__ feat, const int* __restrict__ labels,
        const float* __restrict__ protos, const int* __restrict__ plabels,
        float* __restrict__ Psum, float* __restrict__ expPsum,
        float* __restrict__ PLab, int* __restrict__ nf,
        int* __restrict__ count,
        unsigned short* __restrict__ Fb, unsigned short* __restrict__ Fz,
        float* __restrict__ out) {
    __shared__ unsigned short protoB[128 * PS];
    __shared__ unsigned short featB[16 * FS];
    __shared__ int labL[16];
    __shared__ int plabL[B_PRO];

    const int tid = threadIdx.x;
    const int rowBase = blockIdx.x * 16;

    if (blockIdx.x == 0 && tid == 0) out[0] = 0.f;   // k_final (later) accumulates

    if (tid < B_PRO) plabL[tid] = plabels[tid];
    if (tid >= 128 && tid < 144) labL[tid - 128] = labels[rowBase + tid - 128];

    // stage protos -> bf16 LDS (rows >= 100 zeroed). thread: row tid>>1, half tid&1.
    {
        const int pr = tid >> 1, h = tid & 1;
        unsigned short* dst = &protoB[pr * PS + h * 64];
        if (pr < B_PRO) {
            const float* src = protos + pr * K_DIM + h * 64;
            #pragma unroll
            for (int j = 0; j < 16; ++j) {
                float4 v = ((const float4*)src)[j];
                *(ushort4*)&dst[j * 4] = make_ushort4(f2bf(v.x), f2bf(v.y), f2bf(v.z), f2bf(v.w));
            }
        } else {
            #pragma unroll
            for (int j = 0; j < 16; ++j) *(ushort4*)&dst[j * 4] = make_ushort4(0, 0, 0, 0);
        }
    }

    // stage this thread's feat segment (row rp, cols pq*8..+7) -> LDS + Fb.
    const int rp = tid >> 4, pq = tid & 15;
    float4 fa, fb4;
    {
        const float* src = feat + (size_t)(rowBase + rp) * K_DIM + pq * 8;
        fa  = ((const float4*)src)[0];
        fb4 = ((const float4*)src)[1];
        ushort4 o0 = make_ushort4(f2bf(fa.x), f2bf(fa.y), f2bf(fa.z), f2bf(fa.w));
        ushort4 o1 = make_ushort4(f2bf(fb4.x), f2bf(fb4.y), f2bf(fb4.z), f2bf(fb4.w));
        *(ushort4*)&featB[rp * FS + pq * 8]     = o0;
        *(ushort4*)&featB[rp * FS + pq * 8 + 4] = o1;
        unsigned short* fbd = Fb + (size_t)(rowBase + rp) * K_DIM + pq * 8;
        *(ushort4*)&fbd[0] = o0;
        *(ushort4*)&fbd[4] = o1;
    }
    __syncthreads();

    float acc[8];
    #pragma unroll
    for (int s = 0; s < 8; ++s) acc[s] = 0.f;

    const unsigned short* fRow = &featB[rp * FS];
    for (int kc = 0; kc < K_DIM; kc += 16) {
        uint4 q0 = *(const uint4*)&fRow[kc];
        uint4 q1 = *(const uint4*)&fRow[kc + 8];
        float f[16];
        f[0]=lo_bf(q0.x); f[1]=hi_bf(q0.x); f[2]=lo_bf(q0.y); f[3]=hi_bf(q0.y);
        f[4]=lo_bf(q0.z); f[5]=hi_bf(q0.z); f[6]=lo_bf(q0.w); f[7]=hi_bf(q0.w);
        f[8]=lo_bf(q1.x); f[9]=hi_bf(q1.x); f[10]=lo_bf(q1.y); f[11]=hi_bf(q1.y);
        f[12]=lo_bf(q1.z); f[13]=hi_bf(q1.z); f[14]=lo_bf(q1.w); f[15]=hi_bf(q1.w);
        #pragma unroll
        for (int s = 0; s < 8; ++s) {
            const int b = pq + (s & 3) * 16 + (s >> 2) * 64;
            const unsigned short* pRow = &protoB[b * PS];
            uint4 p0 = *(const uint4*)&pRow[kc];
            uint4 p1 = *(const uint4*)&pRow[kc + 8];
            float a = acc[s];
            a += lo_bf(p0.x)*f[0];  a += hi_bf(p0.x)*f[1];
            a += lo_bf(p0.y)*f[2];  a += hi_bf(p0.y)*f[3];
            a += lo_bf(p0.z)*f[4];  a += hi_bf(p0.z)*f[5];
            a += lo_bf(p0.w)*f[6];  a += hi_bf(p0.w)*f[7];
            a += lo_bf(p1.x)*f[8];  a += hi_bf(p1.x)*f[9];
            a += lo_bf(p1.y)*f[10]; a += hi_bf(p1.y)*f[11];
            a += lo_bf(p1.z)*f[12]; a += hi_bf(p1.z)*f[13];
            a += lo_bf(p1.w)*f[14]; a += hi_bf(p1.w)*f[15];
            acc[s] = a;
        }
    }

    // per-row epilogue: mask b<100, reduce over the 16 pq lanes
    const int lbl = labL[rp];
    float psum = 0.f, esum = 0.f, plab = 0.f, flg = 0.f;
    #pragma unroll
    for (int s = 0; s < 8; ++s) {
        const int b = pq + (s & 3) * 16 + (s >> 2) * 64;
        if (b < B_PRO) {
            const float Pv = acc[s] * INV_T;
            psum += Pv;
            esum += __expf(Pv);
            if (b == lbl) plab += Pv;
            if (plabL[b] == lbl) flg = 1.f;
        }
    }
    for (int off = 1; off < 16; off <<= 1) {
        psum += __shfl_xor(psum, off);
        esum += __shfl_xor(esum, off);
        plab += __shfl_xor(plab, off);
        flg  += __shfl_xor(flg,  off);
    }

    // Fz: novel rows get bf16(C*f), base rows zero (every lane knows flg now)
    {
        const bool nov = (flg == 0.f);
        ushort4 z0 = make_ushort4(0,0,0,0), z1 = z0;
        if (nov) {
            z0 = make_ushort4(f2bf(fa.x*C_SCALE), f2bf(fa.y*C_SCALE),
                              f2bf(fa.z*C_SCALE), f2bf(fa.w*C_SCALE));
            z1 = make_ushort4(f2bf(fb4.x*C_SCALE), f2bf(fb4.y*C_SCALE),
                              f2bf(fb4.z*C_SCALE), f2bf(fb4.w*C_SCALE));
        }
        unsigned short* fzd = Fz + (size_t)(rowBase + rp) * K_DIM + pq * 8;
        *(ushort4*)&fzd[0] = z0;
        *(ushort4*)&fzd[4] = z1;
    }

    if (pq == 0) {
        const int i = rowBase + rp;
        Psum[i] = psum; expPsum[i] = esum; PLab[i] = plab;
        const int nov = (flg > 0.f) ? 0 : 1;
        nf[i] = nov;
        if (nov) atomicAdd(count, 1);
    }
}

// ---------------------------------------------------------------- k_colsum
// gpart[p][col] partial column sums of Fz (fp32). 64 blocks x 256 thr;
// block b covers rows [b*128, b*128+128), halves h=0/1 interleave rows.
__global__ __launch_bounds__(256) void k_colsum(const unsigned short* __restrict__ Fz,
                                                float* __restrict__ gpart) {
    const int tid = threadIdx.x;
    const int col = tid & 127, h = tid >> 7;
    const int row0 = blockIdx.x * 128 + h;
    float acc = 0.f;
    #pragma unroll 8
    for (int r = 0; r < 128; r += 2)
        acc += bf2f(Fz[(size_t)(row0 + r) * K_DIM + col]);
    gpart[(blockIdx.x * 2 + h) * 128 + col] = acc;
}

// ---------------------------------------------------------------- k_main
// Block = 256 thr (4 waves), 64 rows x CJ cols of exp2(D) row-sums.
// A staged once through Blds -> a_frag regs; B register-prefetch
// double-buffered. Per 64-col step each wave owns a 16-col slice:
// 4 ds_read_b128 + 16 MFMA + 16 exp2 + 16 add.
__global__ __launch_bounds__(256, 4) void k_main(const unsigned short* __restrict__ Fb,
                                                 const unsigned short* __restrict__ Fz,
                                                 float* __restrict__ rowSumExp) {
    __shared__ unsigned short Blds[64 * LDA];
    __shared__ float Re[4][64];

    const int colBase = blockIdx.x * CJ;
    const int rowBase = blockIdx.y * 64;
    const int tid = threadIdx.x;
    const int wave = tid >> 6, lane = tid & 63;
    const int quad = lane >> 4, c = lane & 15;

    // stage A (64 rows x 128 bf16) through Blds, then lift to registers
    #pragma unroll
    for (int q = 0; q < 4; ++q) {
        const int idx = tid + q * 256, r = idx >> 4, g = idx & 15;
        *(uint4*)&Blds[r * LDA + g * 8] = ((const uint4*)Fb)[(size_t)(rowBase + r) * 16 + g];
    }
    __syncthreads();
    short8 a_frag[4][4];
    #pragma unroll
    for (int mt = 0; mt < 4; ++mt)
        #pragma unroll
        for (int ks = 0; ks < 4; ++ks)
            a_frag[mt][ks] = *(const short8*)&Blds[(mt * 16 + c) * LDA + ks * 32 + quad * 8];

    // prefetch first B tile (columns colBase..+63 of Fz)
    uint4 pf[4];
    #pragma unroll
    for (int q = 0; q < 4; ++q) {
        const int idx = tid + q * 256, r = idx >> 4, g = idx & 15;
        pf[q] = ((const uint4*)Fz)[(size_t)(colBase + r) * 16 + g];
    }
    __syncthreads();   // all a_frag reads done before Blds is overwritten

    float accE[4][4];
    #pragma unroll
    for (int mt = 0; mt < 4; ++mt)
        #pragma unroll
        for (int r = 0; r < 4; ++r) accE[mt][r] = 0.f;

    for (int js = 0; js < CJ; js += 64) {
        // commit prefetched tile to LDS, then prefetch the next one
        #pragma unroll
        for (int q = 0; q < 4; ++q) {
            const int idx = tid + q * 256, r = idx >> 4, g = idx & 15;
            *(uint4*)&Blds[r * LDA + g * 8] = pf[q];
        }
        if (js + 64 < CJ) {
            #pragma unroll
            for (int q = 0; q < 4; ++q) {
                const int idx = tid + q * 256, r = idx >> 4, g = idx & 15;
                pf[q] = ((const uint4*)Fz)[(size_t)(colBase + js + 64 + r) * 16 + g];
            }
        }
        __syncthreads();

        floatx4 D[4];
        #pragma unroll
        for (int mt = 0; mt < 4; ++mt) D[mt] = (floatx4){0.f, 0.f, 0.f, 0.f};
        #pragma unroll
        for (int ks = 0; ks < 4; ++ks) {
            const short8 b = *(const short8*)&Blds[(wave * 16 + c) * LDA + ks * 32 + quad * 8];
            D[0] = __builtin_amdgcn_mfma_f32_16x16x32_bf16(a_frag[0][ks], b, D[0], 0, 0, 0);
            D[1] = __builtin_amdgcn_mfma_f32_16x16x32_bf16(a_frag[1][ks], b, D[1], 0, 0, 0);
            D[2] = __builtin_amdgcn_mfma_f32_16x16x32_bf16(a_frag[2][ks], b, D[2], 0, 0, 0);
            D[3] = __builtin_amdgcn_mfma_f32_16x16x32_bf16(a_frag[3][ks], b, D[3], 0, 0, 0);
        }
        #pragma unroll
        for (int mt = 0; mt < 4; ++mt)
            #pragma unroll
            for (int r = 0; r < 4; ++r)
                accE[mt][r] += EXP2(D[mt][r]);     // base cols: exp2(0)=1, removed later
        __syncthreads();   // readers done before next store
    }

    // reduce over the 16-lane column group
    #pragma unroll
    for (int mt = 0; mt < 4; ++mt)
        #pragma unroll
        for (int r = 0; r < 4; ++r) {
            float e = accE[mt][r];
            for (int off = 1; off < 16; off <<= 1) e += __shfl_xor(e, off);
            if (c == 0) Re[wave][mt * 16 + quad * 4 + r] = e;
        }
    __syncthreads();
    if (tid < 64) {
        const float e = Re[0][tid] + Re[1][tid] + Re[2][tid] + Re[3][tid];
        atomicAdd(&rowSumExp[rowBase + tid], e);
    }
}

// ---------------------------------------------------------------- k_final
// 512 blocks x 256 thr, 16 rows/block. Preamble: reduce gpart -> g[128] LDS.
// Per row i: sZ = dot(Fb_i, g) (z-scaled), dd = dot(Fb_i, Fz_i) = D_ii.
__global__ __launch_bounds__(256) void k_final(
        const int* __restrict__ nf,
        const float* __restrict__ rowSumExp,
        const float* __restrict__ Psum, const float* __restrict__ expPsum,
        const float* __restrict__ PLab,
        const unsigned short* __restrict__ Fb, const unsigned short* __restrict__ Fz,
        const float* __restrict__ gpart,
        const int* __restrict__ count, float* __restrict__ out) {
    __shared__ float g[128];
    __shared__ float sh[16];
    const int tid = threadIdx.x;

    if (tid < 128) {
        float s = 0.f;
        #pragma unroll 8
        for (int p = 0; p < 128; ++p) s += gpart[p * 128 + tid];
        g[tid] = s;
    }
    __syncthreads();

    const int rp = tid >> 4, u = tid & 15;
    const int i = blockIdx.x * 16 + rp;
    uint4 qb = ((const uint4*)Fb)[(size_t)i * 16 + u];
    uint4 qz = ((const uint4*)Fz)[(size_t)i * 16 + u];
    float sZ = 0.f, dd = 0.f;
    {
        const float* gv = &g[u * 8];
        float fb[8], fz[8];
        fb[0]=lo_bf(qb.x); fb[1]=hi_bf(qb.x); fb[2]=lo_bf(qb.y); fb[3]=hi_bf(qb.y);
        fb[4]=lo_bf(qb.z); fb[5]=hi_bf(qb.z); fb[6]=lo_bf(qb.w); fb[7]=hi_bf(qb.w);
        fz[0]=lo_bf(qz.x); fz[1]=hi_bf(qz.x); fz[2]=lo_bf(qz.y); fz[3]=hi_bf(qz.y);
        fz[4]=lo_bf(qz.z); fz[5]=hi_bf(qz.z); fz[6]=lo_bf(qz.w); fz[7]=hi_bf(qz.w);
        #pragma unroll
        for (int e = 0; e < 8; ++e) { sZ += fb[e] * gv[e]; dd += fb[e] * fz[e]; }
    }
    for (int off = 1; off < 16; off <<= 1) {
        sZ += __shfl_xor(sZ, off);
        dd += __shfl_xor(dd, off);
    }

    if (u == 0) {
        const int Nn = *count;
        const float nzero = (float)(M_TOT - Nn);
        const float sumEadj = rowSumExp[i] - nzero;   // remove base-column exp2(0)=1 terms
        float contrib;
        if (nf[i]) {
            const float cnt = (float)(Nn - 1);
            const float sumE = sumEadj - EXP2(dd);            // remove own diagonal
            const float denom = sumE + Psum[i];               // + RAW proto logit sum (faithful)
            const float sumS_raw = (sZ - dd) * INV_C;         // sum_{j novel, j!=i} dot_ij
            const float num = INV_T * sumS_raw - logf(denom) * cnt;
            const float sc = cnt > 0.f ? cnt : 1.f;
            contrib = -(num / sc);
        } else {
            contrib = -(PLab[i] - logf(sumEadj + expPsum[i]));
        }
        sh[rp] = contrib;
    }
    __syncthreads();
    if (tid == 0) {
        float s = 0.f;
        #pragma unroll
        for (int r = 0; r < 16; ++r) s += sh[r];
        atomicAdd(out, s * (1.0f / (float)M_TOT));
    }
}

// ---------------------------------------------------------------- launch
extern "C" void kernel_launch(void* const* d_in, const int* in_sizes, int n_in,
                              void* d_out, int out_size, void* d_ws, size_t ws_size,
                              hipStream_t stream) {
    const float* feat    = (const float*)d_in[0];
    const int*   labels  = (const int*)d_in[1];
    const float* protos  = (const float*)d_in[2];
    const int*   plabels = (const int*)d_in[3];
    float* out = (float*)d_out;

    char* ws = (char*)d_ws;
    int*   count     = (int*)ws;                         // [0,16)     zeroed
    float* rowSumExp = (float*)(ws + 16);                // [16,32784) zeroed
    float* Psum      = (float*)(ws + 32784);
    float* expPsum   = (float*)(ws + 65552);
    float* PLab      = (float*)(ws + 98320);
    int*   nf        = (int*)(ws + 131088);
    float* gpart     = (float*)(ws + 163856);            // 128 x 128 fp32
    unsigned short* Fb = (unsigned short*)(ws + 229392);            // 2 MB, 16B aligned
    unsigned short* Fz = (unsigned short*)(ws + 229392 + 2097152);  // 2 MB, 16B aligned

    hipMemsetAsync(d_ws, 0, 32784, stream);

    k_proto2<<<M_TOT / 16, 256, 0, stream>>>(feat, labels, protos, plabels,
                                             Psum, expPsum, PLab, nf, count, Fb, Fz, out);
    k_colsum<<<M_TOT / 128, 256, 0, stream>>>(Fz, gpart);
    dim3 gmain(M_TOT / CJ, M_TOT / 64);   // 16 x 128, all active
    k_main<<<gmain, 256, 0, stream>>>(Fb, Fz, rowSumExp);
    k_final<<<M_TOT / 16, 256, 0, stream>>>(nf, rowSumExp, Psum, expPsum, PLab,
                                            Fb, Fz, gpart, count, out);
}

// Round 4
// 174.853 us; speedup vs baseline: 1.2662x; 1.2662x over previous
//
#include <hip/hip_runtime.h>
#include <stdint.h>

// SupConLossWithPrototype on MI355X.
// Only NOVEL columns of S=F F^T/T are ever used:
//   novel i: sumS = sum_{j novel, j!=i} S_ij, sumE = sum_{j novel, j!=i} exp(S_ij)
//   base  i: sumE over novel j only
// No compaction: Fz = novel ? bf16(5*log2e * f) : 0. MFMA D = Fb x Fz^T, then
// exp2(D) row-sums; base columns contribute exp2(0)=1, subtracted as (M-Nn).
// sum_j S_ij via linearity: dot(fb_i, g), g = colsum(Fz) (exact bf16 colsum).
// Pipeline: memset(768B) -> k_proto2 (P terms + Fb + Fz + g + zero rowSumExp)
//           -> k_main (MFMA exp2 row sums) -> k_final (loss).

#define M_TOT 8192
#define K_DIM 128
#define B_PRO 100
#define INV_T 5.0f                          // 1/TEMP
#define C_SCALE 7.2134752044448170f         // 5 * log2(e)
#define INV_C   0.1386294361119891f         // ln2/5
#define CJ    1024                          // column chunk per k_main block
#define LDA   136                           // k_main LDS row stride (bf16)
#define PS    136                           // k_proto2 proto LDS stride
#define FS    136                           // k_proto2 feat LDS stride

#if __has_builtin(__builtin_amdgcn_exp2f)
#define EXP2(x) __builtin_amdgcn_exp2f(x)
#else
#define EXP2(x) __expf((x) * 0.6931471805599453f)
#endif

typedef __attribute__((ext_vector_type(8))) short  short8;   // 8 bf16 (MFMA A/B frag)
typedef __attribute__((ext_vector_type(4))) float  floatx4;  // MFMA C/D frag

__device__ __forceinline__ float bf2f(unsigned short u) {
    union { unsigned int i; float f; } v; v.i = ((unsigned int)u) << 16; return v.f;
}
__device__ __forceinline__ unsigned short f2bf(float x) {   // RNE
    union { float f; unsigned int i; } v; v.f = x;
    return (unsigned short)((v.i + 0x7fffu + ((v.i >> 16) & 1u)) >> 16);
}
__device__ __forceinline__ float lo_bf(unsigned int u) {
    union { unsigned int i; float f; } v; v.i = u << 16; return v.f;
}
__device__ __forceinline__ float hi_bf(unsigned int u) {
    union { unsigned int i; float f; } v; v.i = u & 0xffff0000u; return v.f;
}

// ---------------------------------------------------------------- k_proto2
// 512 blocks x 256 thr; 16 feature rows per block. Emits Psum/expPsum/PLab/nf,
// count, Fb = bf16(f), Fz = novel? bf16(C*f):0, g += colsum(Fz) (exact), and
// zeroes rowSumExp for its rows.
__global__ __launch_bounds__(256) void k_proto2(
        const float* __restrict__ feat, const int* __restrict__ labels,
        const float* __restrict__ protos, const int* __restrict__ plabels,
        float* __restrict__ Psum, float* __restrict__ expPsum,
        float* __restrict__ PLab, int* __restrict__ nf,
        int* __restrict__ count,
        unsigned short* __restrict__ Fb, unsigned short* __restrict__ Fz,
        float* __restrict__ g, float* __restrict__ rowSumExp,
        float* __restrict__ out) {
    __shared__ unsigned short protoB[128 * PS];
    __shared__ unsigned short featB[16 * FS];
    __shared__ float zcol[16][128];
    __shared__ int labL[16];
    __shared__ int plabL[B_PRO];

    const int tid = threadIdx.x;
    const int rowBase = blockIdx.x * 16;

    if (blockIdx.x == 0 && tid == 0) out[0] = 0.f;   // k_final accumulates later

    if (tid < B_PRO) plabL[tid] = plabels[tid];
    if (tid >= 128 && tid < 144) labL[tid - 128] = labels[rowBase + tid - 128];

    // stage protos -> bf16 LDS (rows >= 100 zeroed). thread: row tid>>1, half tid&1.
    {
        const int pr = tid >> 1, h = tid & 1;
        unsigned short* dst = &protoB[pr * PS + h * 64];
        if (pr < B_PRO) {
            const float* src = protos + pr * K_DIM + h * 64;
            #pragma unroll
            for (int j = 0; j < 16; ++j) {
                float4 v = ((const float4*)src)[j];
                *(ushort4*)&dst[j * 4] = make_ushort4(f2bf(v.x), f2bf(v.y), f2bf(v.z), f2bf(v.w));
            }
        } else {
            #pragma unroll
            for (int j = 0; j < 16; ++j) *(ushort4*)&dst[j * 4] = make_ushort4(0, 0, 0, 0);
        }
    }

    // stage this thread's feat segment (row rp, cols pq*8..+7) -> LDS + Fb.
    const int rp = tid >> 4, pq = tid & 15;
    float4 fa, fb4;
    {
        const float* src = feat + (size_t)(rowBase + rp) * K_DIM + pq * 8;
        fa  = ((const float4*)src)[0];
        fb4 = ((const float4*)src)[1];
        ushort4 o0 = make_ushort4(f2bf(fa.x), f2bf(fa.y), f2bf(fa.z), f2bf(fa.w));
        ushort4 o1 = make_ushort4(f2bf(fb4.x), f2bf(fb4.y), f2bf(fb4.z), f2bf(fb4.w));
        *(ushort4*)&featB[rp * FS + pq * 8]     = o0;
        *(ushort4*)&featB[rp * FS + pq * 8 + 4] = o1;
        unsigned short* fbd = Fb + (size_t)(rowBase + rp) * K_DIM + pq * 8;
        *(ushort4*)&fbd[0] = o0;
        *(ushort4*)&fbd[4] = o1;
    }
    if (pq == 0) rowSumExp[rowBase + rp] = 0.f;
    __syncthreads();

    float acc[8];
    #pragma unroll
    for (int s = 0; s < 8; ++s) acc[s] = 0.f;

    const unsigned short* fRow = &featB[rp * FS];
    for (int kc = 0; kc < K_DIM; kc += 16) {
        uint4 q0 = *(const uint4*)&fRow[kc];
        uint4 q1 = *(const uint4*)&fRow[kc + 8];
        float f[16];
        f[0]=lo_bf(q0.x); f[1]=hi_bf(q0.x); f[2]=lo_bf(q0.y); f[3]=hi_bf(q0.y);
        f[4]=lo_bf(q0.z); f[5]=hi_bf(q0.z); f[6]=lo_bf(q0.w); f[7]=hi_bf(q0.w);
        f[8]=lo_bf(q1.x); f[9]=hi_bf(q1.x); f[10]=lo_bf(q1.y); f[11]=hi_bf(q1.y);
        f[12]=lo_bf(q1.z); f[13]=hi_bf(q1.z); f[14]=lo_bf(q1.w); f[15]=hi_bf(q1.w);
        #pragma unroll
        for (int s = 0; s < 8; ++s) {
            const int b = pq + (s & 3) * 16 + (s >> 2) * 64;
            const unsigned short* pRow = &protoB[b * PS];
            uint4 p0 = *(const uint4*)&pRow[kc];
            uint4 p1 = *(const uint4*)&pRow[kc + 8];
            float a = acc[s];
            a += lo_bf(p0.x)*f[0];  a += hi_bf(p0.x)*f[1];
            a += lo_bf(p0.y)*f[2];  a += hi_bf(p0.y)*f[3];
            a += lo_bf(p0.z)*f[4];  a += hi_bf(p0.z)*f[5];
            a += lo_bf(p0.w)*f[6];  a += hi_bf(p0.w)*f[7];
            a += lo_bf(p1.x)*f[8];  a += hi_bf(p1.x)*f[9];
            a += lo_bf(p1.y)*f[10]; a += hi_bf(p1.y)*f[11];
            a += lo_bf(p1.z)*f[12]; a += hi_bf(p1.z)*f[13];
            a += lo_bf(p1.w)*f[14]; a += hi_bf(p1.w)*f[15];
            acc[s] = a;
        }
    }

    // per-row epilogue: mask b<100, reduce over the 16 pq lanes
    const int lbl = labL[rp];
    float psum = 0.f, esum = 0.f, plab = 0.f, flg = 0.f;
    #pragma unroll
    for (int s = 0; s < 8; ++s) {
        const int b = pq + (s & 3) * 16 + (s >> 2) * 64;
        if (b < B_PRO) {
            const float Pv = acc[s] * INV_T;
            psum += Pv;
            esum += __expf(Pv);
            if (b == lbl) plab += Pv;
            if (plabL[b] == lbl) flg = 1.f;
        }
    }
    for (int off = 1; off < 16; off <<= 1) {
        psum += __shfl_xor(psum, off);
        esum += __shfl_xor(esum, off);
        plab += __shfl_xor(plab, off);
        flg  += __shfl_xor(flg,  off);
    }

    // Fz write + zcol (exact bf16 values into LDS for the column sum)
    {
        const bool nov = (flg == 0.f);
        ushort4 z0 = make_ushort4(0,0,0,0), z1 = z0;
        if (nov) {
            z0 = make_ushort4(f2bf(fa.x*C_SCALE), f2bf(fa.y*C_SCALE),
                              f2bf(fa.z*C_SCALE), f2bf(fa.w*C_SCALE));
            z1 = make_ushort4(f2bf(fb4.x*C_SCALE), f2bf(fb4.y*C_SCALE),
                              f2bf(fb4.z*C_SCALE), f2bf(fb4.w*C_SCALE));
        }
        unsigned short* fzd = Fz + (size_t)(rowBase + rp) * K_DIM + pq * 8;
        *(ushort4*)&fzd[0] = z0;
        *(ushort4*)&fzd[4] = z1;
        float* zc = &zcol[rp][pq * 8];
        zc[0] = bf2f(z0.x); zc[1] = bf2f(z0.y); zc[2] = bf2f(z0.z); zc[3] = bf2f(z0.w);
        zc[4] = bf2f(z1.x); zc[5] = bf2f(z1.y); zc[6] = bf2f(z1.z); zc[7] = bf2f(z1.w);
    }

    if (pq == 0) {
        const int i = rowBase + rp;
        Psum[i] = psum; expPsum[i] = esum; PLab[i] = plab;
        const int nov = (flg > 0.f) ? 0 : 1;
        nf[i] = nov;
        if (nov) atomicAdd(count, 1);
    }

    __syncthreads();
    if (tid < 128) {
        float s = 0.f;
        #pragma unroll
        for (int r = 0; r < 16; ++r) s += zcol[r][tid];
        if (s != 0.f) atomicAdd(&g[tid], s);
    }
}

// ---------------------------------------------------------------- k_main
// Block = 256 thr (4 waves), 64 rows x CJ cols of exp2(D) row-sums.
// a_frag register-resident (64 VGPR); B register-prefetched into a
// double-buffered LDS tile -> ONE barrier per 64-col j-step. Per j-step per
// wave: 4 ds_read_b128 + 16 MFMA + 16 exp2 + 16 add.
__global__ __launch_bounds__(256, 3) void k_main(const unsigned short* __restrict__ Fb,
                                                 const unsigned short* __restrict__ Fz,
                                                 float* __restrict__ rowSumExp) {
    __shared__ unsigned short Blds[2][64 * LDA];
    __shared__ float Re[4][64];

    const int colBase = blockIdx.x * CJ;
    const int rowBase = blockIdx.y * 64;
    const int tid = threadIdx.x;
    const int wave = tid >> 6, lane = tid & 63;
    const int quad = lane >> 4, c = lane & 15;

    // stage A (64 rows x 128 bf16) through Blds[0], lift to registers
    #pragma unroll
    for (int q = 0; q < 4; ++q) {
        const int idx = tid + q * 256, r = idx >> 4, gg = idx & 15;
        *(uint4*)&Blds[0][r * LDA + gg * 8] = ((const uint4*)Fb)[(size_t)(rowBase + r) * 16 + gg];
    }
    __syncthreads();
    short8 a_frag[4][4];
    #pragma unroll
    for (int mt = 0; mt < 4; ++mt)
        #pragma unroll
        for (int ks = 0; ks < 4; ++ks)
            a_frag[mt][ks] = *(const short8*)&Blds[0][(mt * 16 + c) * LDA + ks * 32 + quad * 8];

    // prefetch first B tile into registers
    uint4 pf[4];
    #pragma unroll
    for (int q = 0; q < 4; ++q) {
        const int idx = tid + q * 256, r = idx >> 4, gg = idx & 15;
        pf[q] = ((const uint4*)Fz)[(size_t)(colBase + r) * 16 + gg];
    }
    __syncthreads();   // a_frag lifts complete before Blds[0] is overwritten

    float accE[4][4];
    #pragma unroll
    for (int mt = 0; mt < 4; ++mt)
        #pragma unroll
        for (int r = 0; r < 4; ++r) accE[mt][r] = 0.f;

    const int NSTEP = CJ / 64;
    #pragma unroll 1
    for (int js = 0; js < NSTEP; ++js) {
        const int buf = js & 1;
        // commit prefetched tile, then prefetch the next (stays in flight
        // through the compute phase; barrier does not drain VGPR loads)
        #pragma unroll
        for (int q = 0; q < 4; ++q) {
            const int idx = tid + q * 256, r = idx >> 4, gg = idx & 15;
            *(uint4*)&Blds[buf][r * LDA + gg * 8] = pf[q];
        }
        if (js + 1 < NSTEP) {
            #pragma unroll
            for (int q = 0; q < 4; ++q) {
                const int idx = tid + q * 256, r = idx >> 4, gg = idx & 15;
                pf[q] = ((const uint4*)Fz)[(size_t)(colBase + (js + 1) * 64 + r) * 16 + gg];
            }
        }
        __syncthreads();

        floatx4 D[4];
        #pragma unroll
        for (int mt = 0; mt < 4; ++mt) D[mt] = (floatx4){0.f, 0.f, 0.f, 0.f};
        #pragma unroll
        for (int ks = 0; ks < 4; ++ks) {
            const short8 b = *(const short8*)&Blds[buf][(wave * 16 + c) * LDA + ks * 32 + quad * 8];
            D[0] = __builtin_amdgcn_mfma_f32_16x16x32_bf16(a_frag[0][ks], b, D[0], 0, 0, 0);
            D[1] = __builtin_amdgcn_mfma_f32_16x16x32_bf16(a_frag[1][ks], b, D[1], 0, 0, 0);
            D[2] = __builtin_amdgcn_mfma_f32_16x16x32_bf16(a_frag[2][ks], b, D[2], 0, 0, 0);
            D[3] = __builtin_amdgcn_mfma_f32_16x16x32_bf16(a_frag[3][ks], b, D[3], 0, 0, 0);
        }
        #pragma unroll
        for (int mt = 0; mt < 4; ++mt)
            #pragma unroll
            for (int r = 0; r < 4; ++r)
                accE[mt][r] += EXP2(D[mt][r]);   // base cols: exp2(0)=1, removed later
        // no trailing barrier: next iteration writes the OTHER buffer; the
        // per-iteration barrier bounds wave skew to < 1 step.
    }

    // reduce over the 16-lane column group
    #pragma unroll
    for (int mt = 0; mt < 4; ++mt)
        #pragma unroll
        for (int r = 0; r < 4; ++r) {
            float e = accE[mt][r];
            for (int off = 1; off < 16; off <<= 1) e += __shfl_xor(e, off);
            if (c == 0) Re[wave][mt * 16 + quad * 4 + r] = e;
        }
    __syncthreads();
    if (tid < 64) {
        const float e = Re[0][tid] + Re[1][tid] + Re[2][tid] + Re[3][tid];
        atomicAdd(&rowSumExp[rowBase + tid], e);
    }
}

// ---------------------------------------------------------------- k_final
// 512 blocks x 256 thr, 16 rows/block. Per row i: sZ = dot(Fb_i, g)
// (z-scaled), dd = dot(Fb_i, Fz_i) = D_ii.
__global__ __launch_bounds__(256) void k_final(
        const int* __restrict__ nf,
        const float* __restrict__ rowSumExp,
        const float* __restrict__ Psum, const float* __restrict__ expPsum,
        const float* __restrict__ PLab,
        const unsigned short* __restrict__ Fb, const unsigned short* __restrict__ Fz,
        const float* __restrict__ gsrc,
        const int* __restrict__ count, float* __restrict__ out) {
    __shared__ float g[128];
    __shared__ float sh[16];
    const int tid = threadIdx.x;

    if (tid < 128) g[tid] = gsrc[tid];
    __syncthreads();

    const int rp = tid >> 4, u = tid & 15;
    const int i = blockIdx.x * 16 + rp;
    uint4 qb = ((const uint4*)Fb)[(size_t)i * 16 + u];
    uint4 qz = ((const uint4*)Fz)[(size_t)i * 16 + u];
    float sZ = 0.f, dd = 0.f;
    {
        const float* gv = &g[u * 8];
        float fb[8], fz[8];
        fb[0]=lo_bf(qb.x); fb[1]=hi_bf(qb.x); fb[2]=lo_bf(qb.y); fb[3]=hi_bf(qb.y);
        fb[4]=lo_bf(qb.z); fb[5]=hi_bf(qb.z); fb[6]=lo_bf(qb.w); fb[7]=hi_bf(qb.w);
        fz[0]=lo_bf(qz.x); fz[1]=hi_bf(qz.x); fz[2]=lo_bf(qz.y); fz[3]=hi_bf(qz.y);
        fz[4]=lo_bf(qz.z); fz[5]=hi_bf(qz.z); fz[6]=lo_bf(qz.w); fz[7]=hi_bf(qz.w);
        #pragma unroll
        for (int e = 0; e < 8; ++e) { sZ += fb[e] * gv[e]; dd += fb[e] * fz[e]; }
    }
    for (int off = 1; off < 16; off <<= 1) {
        sZ += __shfl_xor(sZ, off);
        dd += __shfl_xor(dd, off);
    }

    if (u == 0) {
        const int Nn = *count;
        const float nzero = (float)(M_TOT - Nn);
        const float sumEadj = rowSumExp[i] - nzero;   // remove base-column exp2(0)=1 terms
        float contrib;
        if (nf[i]) {
            const float cnt = (float)(Nn - 1);
            const float sumE = sumEadj - EXP2(dd);            // remove own diagonal
            const float denom = sumE + Psum[i];               // + RAW proto logit sum (faithful)
            const float sumS_raw = (sZ - dd) * INV_C;         // sum_{j novel, j!=i} dot_ij
            const float num = INV_T * sumS_raw - logf(denom) * cnt;
            const float sc = cnt > 0.f ? cnt : 1.f;
            contrib = -(num / sc);
        } else {
            contrib = -(PLab[i] - logf(sumEadj + expPsum[i]));
        }
        sh[rp] = contrib;
    }
    __syncthreads();
    if (tid == 0) {
        float s = 0.f;
        #pragma unroll
        for (int r = 0; r < 16; ++r) s += sh[r];
        atomicAdd(out, s * (1.0f / (float)M_TOT));
    }
}

// ---------------------------------------------------------------- launch
extern "C" void kernel_launch(void* const* d_in, const int* in_sizes, int n_in,
                              void* d_out, int out_size, void* d_ws, size_t ws_size,
                              hipStream_t stream) {
    const float* feat    = (const float*)d_in[0];
    const int*   labels  = (const int*)d_in[1];
    const float* protos  = (const float*)d_in[2];
    const int*   plabels = (const int*)d_in[3];
    float* out = (float*)d_out;

    char* ws = (char*)d_ws;
    int*   count     = (int*)ws;                 // [0,4)        zeroed
    float* g         = (float*)(ws + 256);       // [256,768)    zeroed
    float* rowSumExp = (float*)(ws + 1024);      // 32 KB, zeroed by k_proto2
    float* Psum      = (float*)(ws + 33792);
    float* expPsum   = (float*)(ws + 66560);
    float* PLab      = (float*)(ws + 99328);
    int*   nf        = (int*)(ws + 132096);
    unsigned short* Fb = (unsigned short*)(ws + 164864);            // 2 MB, 16B aligned
    unsigned short* Fz = (unsigned short*)(ws + 164864 + 2097152);  // 2 MB, 16B aligned

    hipMemsetAsync(ws, 0, 768, stream);

    k_proto2<<<M_TOT / 16, 256, 0, stream>>>(feat, labels, protos, plabels,
                                             Psum, expPsum, PLab, nf, count,
                                             Fb, Fz, g, rowSumExp, out);
    dim3 gmain(M_TOT / CJ, M_TOT / 64);   // 8 x 128, all active, balanced
    k_main<<<gmain, 256, 0, stream>>>(Fb, Fz, rowSumExp);
    k_final<<<M_TOT / 16, 256, 0, stream>>>(nf, rowSumExp, Psum, expPsum, PLab,
                                            Fb, Fz, g, count, out);
}

// Round 5
// 143.052 us; speedup vs baseline: 1.5477x; 1.2223x over previous
//
#include <hip/hip_runtime.h>
#include <stdint.h>

// SupConLossWithPrototype on MI355X.
// Only NOVEL columns of S=F F^T/T are ever used:
//   novel i: sumS = sum_{j novel, j!=i} S_ij, sumE = sum_{j novel, j!=i} exp(S_ij)
//   base  i: sumE over novel j only
// No compaction: Fz = novel ? bf16(5*log2e * f) : 0. MFMA D = Fb x Fz^T, then
// exp2(D) row-sums; base columns contribute exp2(0)=1, subtracted as (M-Nn).
// sum_j S_ij via linearity: dot(fb_i, g), g = colsum(Fz) (exact bf16 colsum).
//
// k_main design (round 5): NO LDS tiles, NO barriers, NO register pipeline.
// Fz (2 MB) is L2-resident (read 128x; grid x-major => blockIdx.x == XCD id,
// each XCD caches only its 256 KB column slice). B-fragments are loaded
// per-MFMA directly from global (16 B/lane b128 gather). Persistent regs:
// a_frag 64 + accE 16 + D 16 -> no spill pressure (rounds 3/4 died to
// compiler scratch-spilling the prefetch pipeline: VGPR_Count=64 + 32-353 MB
// scratch traffic).

#define M_TOT 8192
#define K_DIM 128
#define B_PRO 100
#define INV_T 5.0f                          // 1/TEMP
#define C_SCALE 7.2134752044448170f         // 5 * log2(e)
#define INV_C   0.1386294361119891f         // ln2/5
#define CJ    1024                          // columns per k_main block
#define PS    136                           // k_proto2 proto LDS stride
#define FS    136                           // k_proto2 feat LDS stride

#if __has_builtin(__builtin_amdgcn_exp2f)
#define EXP2(x) __builtin_amdgcn_exp2f(x)
#else
#define EXP2(x) __expf((x) * 0.6931471805599453f)
#endif

typedef __attribute__((ext_vector_type(8))) short  short8;   // 8 bf16 (MFMA A/B frag)
typedef __attribute__((ext_vector_type(4))) float  floatx4;  // MFMA C/D frag

__device__ __forceinline__ float bf2f(unsigned short u) {
    union { unsigned int i; float f; } v; v.i = ((unsigned int)u) << 16; return v.f;
}
__device__ __forceinline__ unsigned short f2bf(float x) {   // RNE
    union { float f; unsigned int i; } v; v.f = x;
    return (unsigned short)((v.i + 0x7fffu + ((v.i >> 16) & 1u)) >> 16);
}
__device__ __forceinline__ float lo_bf(unsigned int u) {
    union { unsigned int i; float f; } v; v.i = u << 16; return v.f;
}
__device__ __forceinline__ float hi_bf(unsigned int u) {
    union { unsigned int i; float f; } v; v.i = u & 0xffff0000u; return v.f;
}

// ---------------------------------------------------------------- k_proto2
// 512 blocks x 256 thr; 16 feature rows per block. Emits Psum/expPsum/PLab/nf,
// count, Fb = bf16(f), Fz = novel? bf16(C*f):0, g += colsum(Fz) (exact), and
// zeroes rowSumExp for its rows.
__global__ __launch_bounds__(256) void k_proto2(
        const float* __restrict__ feat, const int* __restrict__ labels,
        const float* __restrict__ protos, const int* __restrict__ plabels,
        float* __restrict__ Psum, float* __restrict__ expPsum,
        float* __restrict__ PLab, int* __restrict__ nf,
        int* __restrict__ count,
        unsigned short* __restrict__ Fb, unsigned short* __restrict__ Fz,
        float* __restrict__ g, float* __restrict__ rowSumExp,
        float* __restrict__ out) {
    __shared__ unsigned short protoB[128 * PS];
    __shared__ unsigned short featB[16 * FS];
    __shared__ float zcol[16][128];
    __shared__ int labL[16];
    __shared__ int plabL[B_PRO];

    const int tid = threadIdx.x;
    const int rowBase = blockIdx.x * 16;

    if (blockIdx.x == 0 && tid == 0) out[0] = 0.f;   // k_final accumulates later

    if (tid < B_PRO) plabL[tid] = plabels[tid];
    if (tid >= 128 && tid < 144) labL[tid - 128] = labels[rowBase + tid - 128];

    // stage protos -> bf16 LDS (rows >= 100 zeroed). thread: row tid>>1, half tid&1.
    {
        const int pr = tid >> 1, h = tid & 1;
        unsigned short* dst = &protoB[pr * PS + h * 64];
        if (pr < B_PRO) {
            const float* src = protos + pr * K_DIM + h * 64;
            #pragma unroll
            for (int j = 0; j < 16; ++j) {
                float4 v = ((const float4*)src)[j];
                *(ushort4*)&dst[j * 4] = make_ushort4(f2bf(v.x), f2bf(v.y), f2bf(v.z), f2bf(v.w));
            }
        } else {
            #pragma unroll
            for (int j = 0; j < 16; ++j) *(ushort4*)&dst[j * 4] = make_ushort4(0, 0, 0, 0);
        }
    }

    // stage this thread's feat segment (row rp, cols pq*8..+7) -> LDS + Fb.
    const int rp = tid >> 4, pq = tid & 15;
    float4 fa, fb4;
    {
        const float* src = feat + (size_t)(rowBase + rp) * K_DIM + pq * 8;
        fa  = ((const float4*)src)[0];
        fb4 = ((const float4*)src)[1];
        ushort4 o0 = make_ushort4(f2bf(fa.x), f2bf(fa.y), f2bf(fa.z), f2bf(fa.w));
        ushort4 o1 = make_ushort4(f2bf(fb4.x), f2bf(fb4.y), f2bf(fb4.z), f2bf(fb4.w));
        *(ushort4*)&featB[rp * FS + pq * 8]     = o0;
        *(ushort4*)&featB[rp * FS + pq * 8 + 4] = o1;
        unsigned short* fbd = Fb + (size_t)(rowBase + rp) * K_DIM + pq * 8;
        *(ushort4*)&fbd[0] = o0;
        *(ushort4*)&fbd[4] = o1;
    }
    if (pq == 0) rowSumExp[rowBase + rp] = 0.f;
    __syncthreads();

    float acc[8];
    #pragma unroll
    for (int s = 0; s < 8; ++s) acc[s] = 0.f;

    const unsigned short* fRow = &featB[rp * FS];
    for (int kc = 0; kc < K_DIM; kc += 16) {
        uint4 q0 = *(const uint4*)&fRow[kc];
        uint4 q1 = *(const uint4*)&fRow[kc + 8];
        float f[16];
        f[0]=lo_bf(q0.x); f[1]=hi_bf(q0.x); f[2]=lo_bf(q0.y); f[3]=hi_bf(q0.y);
        f[4]=lo_bf(q0.z); f[5]=hi_bf(q0.z); f[6]=lo_bf(q0.w); f[7]=hi_bf(q0.w);
        f[8]=lo_bf(q1.x); f[9]=hi_bf(q1.x); f[10]=lo_bf(q1.y); f[11]=hi_bf(q1.y);
        f[12]=lo_bf(q1.z); f[13]=hi_bf(q1.z); f[14]=lo_bf(q1.w); f[15]=hi_bf(q1.w);
        #pragma unroll
        for (int s = 0; s < 8; ++s) {
            const int b = pq + (s & 3) * 16 + (s >> 2) * 64;
            const unsigned short* pRow = &protoB[b * PS];
            uint4 p0 = *(const uint4*)&pRow[kc];
            uint4 p1 = *(const uint4*)&pRow[kc + 8];
            float a = acc[s];
            a += lo_bf(p0.x)*f[0];  a += hi_bf(p0.x)*f[1];
            a += lo_bf(p0.y)*f[2];  a += hi_bf(p0.y)*f[3];
            a += lo_bf(p0.z)*f[4];  a += hi_bf(p0.z)*f[5];
            a += lo_bf(p0.w)*f[6];  a += hi_bf(p0.w)*f[7];
            a += lo_bf(p1.x)*f[8];  a += hi_bf(p1.x)*f[9];
            a += lo_bf(p1.y)*f[10]; a += hi_bf(p1.y)*f[11];
            a += lo_bf(p1.z)*f[12]; a += hi_bf(p1.z)*f[13];
            a += lo_bf(p1.w)*f[14]; a += hi_bf(p1.w)*f[15];
            acc[s] = a;
        }
    }

    // per-row epilogue: mask b<100, reduce over the 16 pq lanes
    const int lbl = labL[rp];
    float psum = 0.f, esum = 0.f, plab = 0.f, flg = 0.f;
    #pragma unroll
    for (int s = 0; s < 8; ++s) {
        const int b = pq + (s & 3) * 16 + (s >> 2) * 64;
        if (b < B_PRO) {
            const float Pv = acc[s] * INV_T;
            psum += Pv;
            esum += __expf(Pv);
            if (b == lbl) plab += Pv;
            if (plabL[b] == lbl) flg = 1.f;
        }
    }
    for (int off = 1; off < 16; off <<= 1) {
        psum += __shfl_xor(psum, off);
        esum += __shfl_xor(esum, off);
        plab += __shfl_xor(plab, off);
        flg  += __shfl_xor(flg,  off);
    }

    // Fz write + zcol (exact bf16 values into LDS for the column sum)
    {
        const bool nov = (flg == 0.f);
        ushort4 z0 = make_ushort4(0,0,0,0), z1 = z0;
        if (nov) {
            z0 = make_ushort4(f2bf(fa.x*C_SCALE), f2bf(fa.y*C_SCALE),
                              f2bf(fa.z*C_SCALE), f2bf(fa.w*C_SCALE));
            z1 = make_ushort4(f2bf(fb4.x*C_SCALE), f2bf(fb4.y*C_SCALE),
                              f2bf(fb4.z*C_SCALE), f2bf(fb4.w*C_SCALE));
        }
        unsigned short* fzd = Fz + (size_t)(rowBase + rp) * K_DIM + pq * 8;
        *(ushort4*)&fzd[0] = z0;
        *(ushort4*)&fzd[4] = z1;
        float* zc = &zcol[rp][pq * 8];
        zc[0] = bf2f(z0.x); zc[1] = bf2f(z0.y); zc[2] = bf2f(z0.z); zc[3] = bf2f(z0.w);
        zc[4] = bf2f(z1.x); zc[5] = bf2f(z1.y); zc[6] = bf2f(z1.z); zc[7] = bf2f(z1.w);
    }

    if (pq == 0) {
        const int i = rowBase + rp;
        Psum[i] = psum; expPsum[i] = esum; PLab[i] = plab;
        const int nov = (flg > 0.f) ? 0 : 1;
        nf[i] = nov;
        if (nov) atomicAdd(count, 1);
    }

    __syncthreads();
    if (tid < 128) {
        float s = 0.f;
        #pragma unroll
        for (int r = 0; r < 16; ++r) s += zcol[r][tid];
        if (s != 0.f) atomicAdd(&g[tid], s);
    }
}

// ---------------------------------------------------------------- k_main
// Block = 256 thr (4 waves), 64 rows x CJ cols of exp2(D) row-sums.
// a_frag loaded once directly from global (64 VGPR, register-resident —
// no LDS copy exists to re-read). B-fragments streamed from L2 per step:
// lane (c,quad) loads Fz[(col)*128 + ks*32 + quad*8] as one b128. No LDS
// tiles, no barriers, no prefetch registers -> nothing for the allocator
// to spill. Latency hidden by 16 waves/CU.
__global__ __launch_bounds__(256, 2) void k_main(const unsigned short* __restrict__ Fb,
                                                 const unsigned short* __restrict__ Fz,
                                                 float* __restrict__ rowSumExp) {
    __shared__ float Re[4][64];

    const int rowBase = blockIdx.y * 64;
    const int tid = threadIdx.x;
    const int wave = tid >> 6, lane = tid & 63;
    const int quad = lane >> 4, c = lane & 15;

    // A fragments straight from global: rows mt*16+c, k = ks*32+quad*8..+7
    short8 a_frag[4][4];
    #pragma unroll
    for (int mt = 0; mt < 4; ++mt)
        #pragma unroll
        for (int ks = 0; ks < 4; ++ks)
            a_frag[mt][ks] = *(const short8*)(Fb + (size_t)(rowBase + mt * 16 + c) * K_DIM
                                              + ks * 32 + quad * 8);

    float accE[4][4];
    #pragma unroll
    for (int mt = 0; mt < 4; ++mt)
        #pragma unroll
        for (int r = 0; r < 4; ++r) accE[mt][r] = 0.f;

    // this lane's column for step s: colBase + s*64 + wave*16 + c
    const unsigned short* bptr = Fz + (size_t)(blockIdx.x * CJ + wave * 16 + c) * K_DIM
                                 + quad * 8;

    #pragma unroll 1
    for (int s = 0; s < CJ / 64; ++s) {
        const short8 b0 = *(const short8*)(bptr);
        const short8 b1 = *(const short8*)(bptr + 32);
        const short8 b2 = *(const short8*)(bptr + 64);
        const short8 b3 = *(const short8*)(bptr + 96);
        bptr += 64 * K_DIM;

        floatx4 D[4];
        #pragma unroll
        for (int mt = 0; mt < 4; ++mt) D[mt] = (floatx4){0.f, 0.f, 0.f, 0.f};
        #pragma unroll
        for (int mt = 0; mt < 4; ++mt) {
            D[mt] = __builtin_amdgcn_mfma_f32_16x16x32_bf16(a_frag[mt][0], b0, D[mt], 0, 0, 0);
            D[mt] = __builtin_amdgcn_mfma_f32_16x16x32_bf16(a_frag[mt][1], b1, D[mt], 0, 0, 0);
            D[mt] = __builtin_amdgcn_mfma_f32_16x16x32_bf16(a_frag[mt][2], b2, D[mt], 0, 0, 0);
            D[mt] = __builtin_amdgcn_mfma_f32_16x16x32_bf16(a_frag[mt][3], b3, D[mt], 0, 0, 0);
        }
        #pragma unroll
        for (int mt = 0; mt < 4; ++mt)
            #pragma unroll
            for (int r = 0; r < 4; ++r)
                accE[mt][r] += EXP2(D[mt][r]);   // base cols: exp2(0)=1, removed later
    }

    // reduce over the 16-lane column group
    #pragma unroll
    for (int mt = 0; mt < 4; ++mt)
        #pragma unroll
        for (int r = 0; r < 4; ++r) {
            float e = accE[mt][r];
            for (int off = 1; off < 16; off <<= 1) e += __shfl_xor(e, off);
            if (c == 0) Re[wave][mt * 16 + quad * 4 + r] = e;
        }
    __syncthreads();
    if (tid < 64) {
        const float e = Re[0][tid] + Re[1][tid] + Re[2][tid] + Re[3][tid];
        atomicAdd(&rowSumExp[rowBase + tid], e);
    }
}

// ---------------------------------------------------------------- k_final
// 512 blocks x 256 thr, 16 rows/block. Per row i: sZ = dot(Fb_i, g)
// (z-scaled), dd = dot(Fb_i, Fz_i) = D_ii.
__global__ __launch_bounds__(256) void k_final(
        const int* __restrict__ nf,
        const float* __restrict__ rowSumExp,
        const float* __restrict__ Psum, const float* __restrict__ expPsum,
        const float* __restrict__ PLab,
        const unsigned short* __restrict__ Fb, const unsigned short* __restrict__ Fz,
        const float* __restrict__ gsrc,
        const int* __restrict__ count, float* __restrict__ out) {
    __shared__ float g[128];
    __shared__ float sh[16];
    const int tid = threadIdx.x;

    if (tid < 128) g[tid] = gsrc[tid];
    __syncthreads();

    const int rp = tid >> 4, u = tid & 15;
    const int i = blockIdx.x * 16 + rp;
    uint4 qb = ((const uint4*)Fb)[(size_t)i * 16 + u];
    uint4 qz = ((const uint4*)Fz)[(size_t)i * 16 + u];
    float sZ = 0.f, dd = 0.f;
    {
        const float* gv = &g[u * 8];
        float fb[8], fz[8];
        fb[0]=lo_bf(qb.x); fb[1]=hi_bf(qb.x); fb[2]=lo_bf(qb.y); fb[3]=hi_bf(qb.y);
        fb[4]=lo_bf(qb.z); fb[5]=hi_bf(qb.z); fb[6]=lo_bf(qb.w); fb[7]=hi_bf(qb.w);
        fz[0]=lo_bf(qz.x); fz[1]=hi_bf(qz.x); fz[2]=lo_bf(qz.y); fz[3]=hi_bf(qz.y);
        fz[4]=lo_bf(qz.z); fz[5]=hi_bf(qz.z); fz[6]=lo_bf(qz.w); fz[7]=hi_bf(qz.w);
        #pragma unroll
        for (int e = 0; e < 8; ++e) { sZ += fb[e] * gv[e]; dd += fb[e] * fz[e]; }
    }
    for (int off = 1; off < 16; off <<= 1) {
        sZ += __shfl_xor(sZ, off);
        dd += __shfl_xor(dd, off);
    }

    if (u == 0) {
        const int Nn = *count;
        const float nzero = (float)(M_TOT - Nn);
        const float sumEadj = rowSumExp[i] - nzero;   // remove base-column exp2(0)=1 terms
        float contrib;
        if (nf[i]) {
            const float cnt = (float)(Nn - 1);
            const float sumE = sumEadj - EXP2(dd);            // remove own diagonal
            const float denom = sumE + Psum[i];               // + RAW proto logit sum (faithful)
            const float sumS_raw = (sZ - dd) * INV_C;         // sum_{j novel, j!=i} dot_ij
            const float num = INV_T * sumS_raw - logf(denom) * cnt;
            const float sc = cnt > 0.f ? cnt : 1.f;
            contrib = -(num / sc);
        } else {
            contrib = -(PLab[i] - logf(sumEadj + expPsum[i]));
        }
        sh[rp] = contrib;
    }
    __syncthreads();
    if (tid == 0) {
        float s = 0.f;
        #pragma unroll
        for (int r = 0; r < 16; ++r) s += sh[r];
        atomicAdd(out, s * (1.0f / (float)M_TOT));
    }
}

// ---------------------------------------------------------------- launch
extern "C" void kernel_launch(void* const* d_in, const int* in_sizes, int n_in,
                              void* d_out, int out_size, void* d_ws, size_t ws_size,
                              hipStream_t stream) {
    const float* feat    = (const float*)d_in[0];
    const int*   labels  = (const int*)d_in[1];
    const float* protos  = (const float*)d_in[2];
    const int*   plabels = (const int*)d_in[3];
    float* out = (float*)d_out;

    char* ws = (char*)d_ws;
    int*   count     = (int*)ws;                 // [0,4)        zeroed
    float* g         = (float*)(ws + 256);       // [256,768)    zeroed
    float* rowSumExp = (float*)(ws + 1024);      // 32 KB, zeroed by k_proto2
    float* Psum      = (float*)(ws + 33792);
    float* expPsum   = (float*)(ws + 66560);
    float* PLab      = (float*)(ws + 99328);
    int*   nf        = (int*)(ws + 132096);
    unsigned short* Fb = (unsigned short*)(ws + 164864);            // 2 MB, 16B aligned
    unsigned short* Fz = (unsigned short*)(ws + 164864 + 2097152);  // 2 MB, 16B aligned

    hipMemsetAsync(ws, 0, 768, stream);

    k_proto2<<<M_TOT / 16, 256, 0, stream>>>(feat, labels, protos, plabels,
                                             Psum, expPsum, PLab, nf, count,
                                             Fb, Fz, g, rowSumExp, out);
    dim3 gmain(M_TOT / CJ, M_TOT / 64);   // 8 x 128; blockIdx.x == XCD -> L2-partitioned Fz
    k_main<<<gmain, 256, 0, stream>>>(Fb, Fz, rowSumExp);
    k_final<<<M_TOT / 16, 256, 0, stream>>>(nf, rowSumExp, Psum, expPsum, PLab,
                                            Fb, Fz, g, count, out);
}

// Round 6
// 133.658 us; speedup vs baseline: 1.6564x; 1.0703x over previous
//
#include <hip/hip_runtime.h>
#include <stdint.h>

// SupConLossWithPrototype on MI355X.
// Only NOVEL columns of S=F F^T/T are ever used:
//   novel i: sumS = sum_{j novel, j!=i} S_ij, sumE = sum_{j novel, j!=i} exp(S_ij)
//   base  i: sumE over novel j only
// No compaction: Fz = novel ? bf16(5*log2e * f) : 0. MFMA D = Fb x Fz^T, then
// exp2(D) row-sums; base columns contribute exp2(0)=1, subtracted as (M-Nn).
// sum_j S_ij via linearity: dot(fb_i, g), g = colsum(Fz) (exact bf16 colsum).
//
// Round 6: k_main keeps round-5's barrier-free direct-from-L2 streaming but
// adds a 1-deep REGISTER prefetch of the next B-fragments (direct MFMA
// operands — nothing routed through LDS, so the allocator has no commit
// phase to spill around; rounds 3/4 spilled exactly there). All atomics and
// the memset dispatch are gone: k_main writes per-chunk partial row sums,
// k_proto2 writes per-block gpart/nfcnt partials, k_final reduces both.

#define M_TOT 8192
#define K_DIM 128
#define B_PRO 100
#define INV_T 5.0f                          // 1/TEMP
#define C_SCALE 7.2134752044448170f         // 5 * log2(e)
#define INV_C   0.1386294361119891f         // ln2/5
#define CJ    1024                          // columns per k_main block
#define NCHUNK (M_TOT / CJ)                 // 8 column chunks
#define PS    136                           // k_proto2 proto LDS stride
#define FS    136                           // k_proto2 feat LDS stride

#if __has_builtin(__builtin_amdgcn_exp2f)
#define EXP2(x) __builtin_amdgcn_exp2f(x)
#else
#define EXP2(x) __expf((x) * 0.6931471805599453f)
#endif

typedef __attribute__((ext_vector_type(8))) short  short8;   // 8 bf16 (MFMA A/B frag)
typedef __attribute__((ext_vector_type(4))) float  floatx4;  // MFMA C/D frag

__device__ __forceinline__ float bf2f(unsigned short u) {
    union { unsigned int i; float f; } v; v.i = ((unsigned int)u) << 16; return v.f;
}
__device__ __forceinline__ unsigned short f2bf(float x) {   // RNE
    union { float f; unsigned int i; } v; v.f = x;
    return (unsigned short)((v.i + 0x7fffu + ((v.i >> 16) & 1u)) >> 16);
}
__device__ __forceinline__ float lo_bf(unsigned int u) {
    union { unsigned int i; float f; } v; v.i = u << 16; return v.f;
}
__device__ __forceinline__ float hi_bf(unsigned int u) {
    union { unsigned int i; float f; } v; v.i = u & 0xffff0000u; return v.f;
}

// ---------------------------------------------------------------- k_proto2
// 512 blocks x 256 thr; 16 feature rows per block. Emits Psum/expPsum/PLab/nf,
// Fb = bf16(f), Fz = novel? bf16(C*f):0, gpart[block] = block colsum(Fz),
// nfcnt[block] = block novel count. Block 0 zeroes out[0].
__global__ __launch_bounds__(256) void k_proto2(
        const float* __restrict__ feat, const int* __restrict__ labels,
        const float* __restrict__ protos, const int* __restrict__ plabels,
        float* __restrict__ Psum, float* __restrict__ expPsum,
        float* __restrict__ PLab, int* __restrict__ nf,
        int* __restrict__ nfcnt,
        unsigned short* __restrict__ Fb, unsigned short* __restrict__ Fz,
        float* __restrict__ gpart, float* __restrict__ out) {
    __shared__ unsigned short protoB[128 * PS];
    __shared__ unsigned short featB[16 * FS];
    __shared__ float zcol[16][128];
    __shared__ int labL[16];
    __shared__ int plabL[B_PRO];
    __shared__ int novL[16];

    const int tid = threadIdx.x;
    const int rowBase = blockIdx.x * 16;

    if (blockIdx.x == 0 && tid == 0) out[0] = 0.f;   // k_final accumulates later

    if (tid < B_PRO) plabL[tid] = plabels[tid];
    if (tid >= 128 && tid < 144) labL[tid - 128] = labels[rowBase + tid - 128];

    // stage protos -> bf16 LDS (rows >= 100 zeroed). thread: row tid>>1, half tid&1.
    {
        const int pr = tid >> 1, h = tid & 1;
        unsigned short* dst = &protoB[pr * PS + h * 64];
        if (pr < B_PRO) {
            const float* src = protos + pr * K_DIM + h * 64;
            #pragma unroll
            for (int j = 0; j < 16; ++j) {
                float4 v = ((const float4*)src)[j];
                *(ushort4*)&dst[j * 4] = make_ushort4(f2bf(v.x), f2bf(v.y), f2bf(v.z), f2bf(v.w));
            }
        } else {
            #pragma unroll
            for (int j = 0; j < 16; ++j) *(ushort4*)&dst[j * 4] = make_ushort4(0, 0, 0, 0);
        }
    }

    // stage this thread's feat segment (row rp, cols pq*8..+7) -> LDS + Fb.
    const int rp = tid >> 4, pq = tid & 15;
    float4 fa, fb4;
    {
        const float* src = feat + (size_t)(rowBase + rp) * K_DIM + pq * 8;
        fa  = ((const float4*)src)[0];
        fb4 = ((const float4*)src)[1];
        ushort4 o0 = make_ushort4(f2bf(fa.x), f2bf(fa.y), f2bf(fa.z), f2bf(fa.w));
        ushort4 o1 = make_ushort4(f2bf(fb4.x), f2bf(fb4.y), f2bf(fb4.z), f2bf(fb4.w));
        *(ushort4*)&featB[rp * FS + pq * 8]     = o0;
        *(ushort4*)&featB[rp * FS + pq * 8 + 4] = o1;
        unsigned short* fbd = Fb + (size_t)(rowBase + rp) * K_DIM + pq * 8;
        *(ushort4*)&fbd[0] = o0;
        *(ushort4*)&fbd[4] = o1;
    }
    __syncthreads();

    float acc[8];
    #pragma unroll
    for (int s = 0; s < 8; ++s) acc[s] = 0.f;

    const unsigned short* fRow = &featB[rp * FS];
    for (int kc = 0; kc < K_DIM; kc += 16) {
        uint4 q0 = *(const uint4*)&fRow[kc];
        uint4 q1 = *(const uint4*)&fRow[kc + 8];
        float f[16];
        f[0]=lo_bf(q0.x); f[1]=hi_bf(q0.x); f[2]=lo_bf(q0.y); f[3]=hi_bf(q0.y);
        f[4]=lo_bf(q0.z); f[5]=hi_bf(q0.z); f[6]=lo_bf(q0.w); f[7]=hi_bf(q0.w);
        f[8]=lo_bf(q1.x); f[9]=hi_bf(q1.x); f[10]=lo_bf(q1.y); f[11]=hi_bf(q1.y);
        f[12]=lo_bf(q1.z); f[13]=hi_bf(q1.z); f[14]=lo_bf(q1.w); f[15]=hi_bf(q1.w);
        #pragma unroll
        for (int s = 0; s < 8; ++s) {
            const int b = pq + (s & 3) * 16 + (s >> 2) * 64;
            const unsigned short* pRow = &protoB[b * PS];
            uint4 p0 = *(const uint4*)&pRow[kc];
            uint4 p1 = *(const uint4*)&pRow[kc + 8];
            float a = acc[s];
            a += lo_bf(p0.x)*f[0];  a += hi_bf(p0.x)*f[1];
            a += lo_bf(p0.y)*f[2];  a += hi_bf(p0.y)*f[3];
            a += lo_bf(p0.z)*f[4];  a += hi_bf(p0.z)*f[5];
            a += lo_bf(p0.w)*f[6];  a += hi_bf(p0.w)*f[7];
            a += lo_bf(p1.x)*f[8];  a += hi_bf(p1.x)*f[9];
            a += lo_bf(p1.y)*f[10]; a += hi_bf(p1.y)*f[11];
            a += lo_bf(p1.z)*f[12]; a += hi_bf(p1.z)*f[13];
            a += lo_bf(p1.w)*f[14]; a += hi_bf(p1.w)*f[15];
            acc[s] = a;
        }
    }

    // per-row epilogue: mask b<100, reduce over the 16 pq lanes
    const int lbl = labL[rp];
    float psum = 0.f, esum = 0.f, plab = 0.f, flg = 0.f;
    #pragma unroll
    for (int s = 0; s < 8; ++s) {
        const int b = pq + (s & 3) * 16 + (s >> 2) * 64;
        if (b < B_PRO) {
            const float Pv = acc[s] * INV_T;
            psum += Pv;
            esum += __expf(Pv);
            if (b == lbl) plab += Pv;
            if (plabL[b] == lbl) flg = 1.f;
        }
    }
    for (int off = 1; off < 16; off <<= 1) {
        psum += __shfl_xor(psum, off);
        esum += __shfl_xor(esum, off);
        plab += __shfl_xor(plab, off);
        flg  += __shfl_xor(flg,  off);
    }

    // Fz write + zcol (exact bf16 values into LDS for the column sum)
    {
        const bool nov = (flg == 0.f);
        ushort4 z0 = make_ushort4(0,0,0,0), z1 = z0;
        if (nov) {
            z0 = make_ushort4(f2bf(fa.x*C_SCALE), f2bf(fa.y*C_SCALE),
                              f2bf(fa.z*C_SCALE), f2bf(fa.w*C_SCALE));
            z1 = make_ushort4(f2bf(fb4.x*C_SCALE), f2bf(fb4.y*C_SCALE),
                              f2bf(fb4.z*C_SCALE), f2bf(fb4.w*C_SCALE));
        }
        unsigned short* fzd = Fz + (size_t)(rowBase + rp) * K_DIM + pq * 8;
        *(ushort4*)&fzd[0] = z0;
        *(ushort4*)&fzd[4] = z1;
        float* zc = &zcol[rp][pq * 8];
        zc[0] = bf2f(z0.x); zc[1] = bf2f(z0.y); zc[2] = bf2f(z0.z); zc[3] = bf2f(z0.w);
        zc[4] = bf2f(z1.x); zc[5] = bf2f(z1.y); zc[6] = bf2f(z1.z); zc[7] = bf2f(z1.w);
    }

    if (pq == 0) {
        const int i = rowBase + rp;
        Psum[i] = psum; expPsum[i] = esum; PLab[i] = plab;
        const int nov = (flg > 0.f) ? 0 : 1;
        nf[i] = nov;
        novL[rp] = nov;
    }

    __syncthreads();
    if (tid < 128) {
        float s = 0.f;
        #pragma unroll
        for (int r = 0; r < 16; ++r) s += zcol[r][tid];
        gpart[blockIdx.x * 128 + tid] = s;         // non-atomic partial
    } else if (tid == 255) {
        int c = 0;
        #pragma unroll
        for (int r = 0; r < 16; ++r) c += novL[r];
        nfcnt[blockIdx.x] = c;                     // non-atomic partial
    }
}

// ---------------------------------------------------------------- k_main
// Block = 256 thr (4 waves), 64 rows x CJ cols of exp2(D) row-sums.
// a_frag loaded once from global (64 VGPR, register-resident). B-fragments
// streamed from L2 with a 1-deep register prefetch: step s+1's 4 b128 loads
// issue before step s's MFMAs, so the vmcnt wait covers a full compute
// phase. No LDS tiles, no barriers. Partial row sums stored non-atomically
// per column chunk.
__global__ __launch_bounds__(256, 2) void k_main(const unsigned short* __restrict__ Fb,
                                                 const unsigned short* __restrict__ Fz,
                                                 float* __restrict__ rowSumPart) {
    __shared__ float Re[4][64];

    const int rowBase = blockIdx.y * 64;
    const int tid = threadIdx.x;
    const int wave = tid >> 6, lane = tid & 63;
    const int quad = lane >> 4, c = lane & 15;

    // A fragments straight from global: rows mt*16+c, k = ks*32+quad*8..+7
    short8 a_frag[4][4];
    #pragma unroll
    for (int mt = 0; mt < 4; ++mt)
        #pragma unroll
        for (int ks = 0; ks < 4; ++ks)
            a_frag[mt][ks] = *(const short8*)(Fb + (size_t)(rowBase + mt * 16 + c) * K_DIM
                                              + ks * 32 + quad * 8);

    float accE[4][4];
    #pragma unroll
    for (int mt = 0; mt < 4; ++mt)
        #pragma unroll
        for (int r = 0; r < 4; ++r) accE[mt][r] = 0.f;

    // this lane's column for step s: colBase + s*64 + wave*16 + c
    const unsigned short* bptr = Fz + (size_t)(blockIdx.x * CJ + wave * 16 + c) * K_DIM
                                 + quad * 8;
    short8 c0 = *(const short8*)(bptr);
    short8 c1 = *(const short8*)(bptr + 32);
    short8 c2 = *(const short8*)(bptr + 64);
    short8 c3 = *(const short8*)(bptr + 96);

    const int NSTEP = CJ / 64;
    #pragma unroll 1
    for (int s = 0; s < NSTEP; ++s) {
        // prefetch next step's fragments (last iter: reload same addr — in
        // bounds, result unused)
        const unsigned short* np = bptr + ((s + 1 < NSTEP) ? (size_t)(64 * K_DIM) : 0);
        short8 n0 = *(const short8*)(np);
        short8 n1 = *(const short8*)(np + 32);
        short8 n2 = *(const short8*)(np + 64);
        short8 n3 = *(const short8*)(np + 96);
        bptr = np;

        floatx4 D[4];
        #pragma unroll
        for (int mt = 0; mt < 4; ++mt) D[mt] = (floatx4){0.f, 0.f, 0.f, 0.f};
        #pragma unroll
        for (int mt = 0; mt < 4; ++mt) {
            D[mt] = __builtin_amdgcn_mfma_f32_16x16x32_bf16(a_frag[mt][0], c0, D[mt], 0, 0, 0);
            D[mt] = __builtin_amdgcn_mfma_f32_16x16x32_bf16(a_frag[mt][1], c1, D[mt], 0, 0, 0);
            D[mt] = __builtin_amdgcn_mfma_f32_16x16x32_bf16(a_frag[mt][2], c2, D[mt], 0, 0, 0);
            D[mt] = __builtin_amdgcn_mfma_f32_16x16x32_bf16(a_frag[mt][3], c3, D[mt], 0, 0, 0);
        }
        #pragma unroll
        for (int mt = 0; mt < 4; ++mt)
            #pragma unroll
            for (int r = 0; r < 4; ++r)
                accE[mt][r] += EXP2(D[mt][r]);   // base cols: exp2(0)=1, removed later

        c0 = n0; c1 = n1; c2 = n2; c3 = n3;
    }

    // reduce over the 16-lane column group
    #pragma unroll
    for (int mt = 0; mt < 4; ++mt)
        #pragma unroll
        for (int r = 0; r < 4; ++r) {
            float e = accE[mt][r];
            for (int off = 1; off < 16; off <<= 1) e += __shfl_xor(e, off);
            if (c == 0) Re[wave][mt * 16 + quad * 4 + r] = e;
        }
    __syncthreads();
    if (tid < 64) {
        const float e = Re[0][tid] + Re[1][tid] + Re[2][tid] + Re[3][tid];
        rowSumPart[(size_t)blockIdx.x * M_TOT + rowBase + tid] = e;   // block-unique
    }
}

// ---------------------------------------------------------------- k_final
// 512 blocks x 256 thr, 16 rows/block. Preamble: g[128] = sum of 512 gpart
// rows; Nn = sum of nfcnt. Per row i: sZ = dot(Fb_i, g), dd = dot(Fb_i,Fz_i)
// = D_ii; sumE = sum over the NCHUNK rowSumPart partials (lane-parallel).
__global__ __launch_bounds__(256) void k_final(
        const int* __restrict__ nf,
        const float* __restrict__ rowSumPart,
        const float* __restrict__ Psum, const float* __restrict__ expPsum,
        const float* __restrict__ PLab,
        const unsigned short* __restrict__ Fb, const unsigned short* __restrict__ Fz,
        const float* __restrict__ gpart, const int* __restrict__ nfcnt,
        float* __restrict__ out) {
    __shared__ float g[128];
    __shared__ float gtmp[128];
    __shared__ float sh[16];
    __shared__ int shNn;
    const int tid = threadIdx.x;

    // g: two half-sums over the 512 gpart rows
    {
        const int col = tid & 127, h = tid >> 7;
        float s = 0.f;
        #pragma unroll 8
        for (int r = h * 256; r < h * 256 + 256; ++r) s += gpart[r * 128 + col];
        if (h) gtmp[col] = s; else g[col] = s;
    }
    // Nn: wave 0 reduces nfcnt[512]
    if (tid < 64) {
        int cs = 0;
        #pragma unroll
        for (int r = 0; r < 8; ++r) cs += nfcnt[tid + 64 * r];
        for (int off = 1; off < 64; off <<= 1) cs += __shfl_xor(cs, off);
        if (tid == 0) shNn = cs;
    }
    __syncthreads();
    if (tid < 128) g[tid] += gtmp[tid];
    __syncthreads();

    const int rp = tid >> 4, u = tid & 15;
    const int i = blockIdx.x * 16 + rp;
    uint4 qb = ((const uint4*)Fb)[(size_t)i * 16 + u];
    uint4 qz = ((const uint4*)Fz)[(size_t)i * 16 + u];
    float sZ = 0.f, dd = 0.f;
    {
        const float* gv = &g[u * 8];
        float fb[8], fz[8];
        fb[0]=lo_bf(qb.x); fb[1]=hi_bf(qb.x); fb[2]=lo_bf(qb.y); fb[3]=hi_bf(qb.y);
        fb[4]=lo_bf(qb.z); fb[5]=hi_bf(qb.z); fb[6]=lo_bf(qb.w); fb[7]=hi_bf(qb.w);
        fz[0]=lo_bf(qz.x); fz[1]=hi_bf(qz.x); fz[2]=lo_bf(qz.y); fz[3]=hi_bf(qz.y);
        fz[4]=lo_bf(qz.z); fz[5]=hi_bf(qz.z); fz[6]=lo_bf(qz.w); fz[7]=hi_bf(qz.w);
        #pragma unroll
        for (int e = 0; e < 8; ++e) { sZ += fb[e] * gv[e]; dd += fb[e] * fz[e]; }
    }
    // rowSumExp partials: lanes u < NCHUNK each grab one chunk's partial
    float ep = (u < NCHUNK) ? rowSumPart[(size_t)u * M_TOT + i] : 0.f;
    for (int off = 1; off < 16; off <<= 1) {
        sZ += __shfl_xor(sZ, off);
        dd += __shfl_xor(dd, off);
        ep += __shfl_xor(ep, off);
    }

    if (u == 0) {
        const int Nn = shNn;
        const float nzero = (float)(M_TOT - Nn);
        const float sumEadj = ep - nzero;             // remove base-column exp2(0)=1 terms
        float contrib;
        if (nf[i]) {
            const float cnt = (float)(Nn - 1);
            const float sumE = sumEadj - EXP2(dd);            // remove own diagonal
            const float denom = sumE + Psum[i];               // + RAW proto logit sum (faithful)
            const float sumS_raw = (sZ - dd) * INV_C;         // sum_{j novel, j!=i} dot_ij
            const float num = INV_T * sumS_raw - logf(denom) * cnt;
            const float sc = cnt > 0.f ? cnt : 1.f;
            contrib = -(num / sc);
        } else {
            contrib = -(PLab[i] - logf(sumEadj + expPsum[i]));
        }
        sh[rp] = contrib;
    }
    __syncthreads();
    if (tid == 0) {
        float s = 0.f;
        #pragma unroll
        for (int r = 0; r < 16; ++r) s += sh[r];
        atomicAdd(out, s * (1.0f / (float)M_TOT));
    }
}

// ---------------------------------------------------------------- launch
extern "C" void kernel_launch(void* const* d_in, const int* in_sizes, int n_in,
                              void* d_out, int out_size, void* d_ws, size_t ws_size,
                              hipStream_t stream) {
    const float* feat    = (const float*)d_in[0];
    const int*   labels  = (const int*)d_in[1];
    const float* protos  = (const float*)d_in[2];
    const int*   plabels = (const int*)d_in[3];
    float* out = (float*)d_out;

    char* ws = (char*)d_ws;
    int*   nfcnt      = (int*)ws;                    // 512 ints
    float* gpart      = (float*)(ws + 4096);         // 512 x 128 fp32 (256 KB)
    float* rowSumPart = (float*)(ws + 266240);       // NCHUNK x 8192 fp32 (256 KB)
    float* Psum       = (float*)(ws + 528384);
    float* expPsum    = (float*)(ws + 561152);
    float* PLab       = (float*)(ws + 593920);
    int*   nf         = (int*)(ws + 626688);
    unsigned short* Fb = (unsigned short*)(ws + 659456);            // 2 MB, 16B aligned
    unsigned short* Fz = (unsigned short*)(ws + 659456 + 2097152);  // 2 MB, 16B aligned

    k_proto2<<<M_TOT / 16, 256, 0, stream>>>(feat, labels, protos, plabels,
                                             Psum, expPsum, PLab, nf, nfcnt,
                                             Fb, Fz, gpart, out);
    dim3 gmain(NCHUNK, M_TOT / 64);   // 8 x 128; blockIdx.x == XCD -> L2-partitioned Fz
    k_main<<<gmain, 256, 0, stream>>>(Fb, Fz, rowSumPart);
    k_final<<<M_TOT / 16, 256, 0, stream>>>(nf, rowSumPart, Psum, expPsum, PLab,
                                            Fb, Fz, gpart, nfcnt, out);
}